// Round 14
// baseline (162.258 us; speedup 1.0000x reference)
//
#include <hip/hip_runtime.h>
#include <math.h>

// ---------------------------------------------------------------------------
// EMD layer (Sinkhorn-OT logits) for MI355X.
// support: [32,512,8,8] f32, query: [256,512,8,8] f32 -> logits [256,32] f32.
//
// R25: R24 + over-relaxed Sinkhorn (SOR, omega=1.4), fixed point UNCHANGED.
//   Observed contraction c~0.68 (~30 iters to 1e-5). Extrapolating the
//   carried w: w_car = w_prev + 1.4*(F(w_prev)-w_prev) maps eigenvalues
//   l -> 1-w+wl: rate 0.68 -> ~0.55 => ~19 iters (-35%). Sinkhorn's
//   linearized map has non-negative spectrum (Hilbert-metric contraction),
//   so omega=1.4 cannot diverge; positivity guard max(., 0.1*w_own)
//   forbids overshoot through zero; it=0 seeds plain. Convergence check
//   unchanged (|F(w_prev)-w_prev| <= 1e-5 w) -> same exit accuracy.
//   Cost: 2 VALU + 1 clamp per ~244-cycle iteration.
//   norm (float4 both passes) and everything else = R24 verbatim.
// ---------------------------------------------------------------------------

#define DEV static __device__ __forceinline__

typedef _Float16 half8 __attribute__((ext_vector_type(8)));
typedef float floatx4 __attribute__((ext_vector_type(4)));
typedef float floatx2 __attribute__((ext_vector_type(2)));

DEV float fast_rcp(float x) {
#if __has_builtin(__builtin_amdgcn_rcpf)
    return __builtin_amdgcn_rcpf(x);
#else
    return 1.0f / x;
#endif
}
DEV float fexp2(float x) {
#if __has_builtin(__builtin_amdgcn_exp2f)
    return __builtin_amdgcn_exp2f(x);
#else
    return exp2f(x);
#endif
}
DEV float flog2(float x) {
#if __has_builtin(__builtin_amdgcn_logf)
    return __builtin_amdgcn_logf(x);
#else
    return log2f(x);
#endif
}
DEV floatx2 pk_mul(floatx2 a, floatx2 b) {
    floatx2 d;
    asm("v_pk_mul_f32 %0, %1, %2" : "=v"(d) : "v"(a), "v"(b));
    return d;
}
DEV floatx2 pk_fma(floatx2 a, floatx2 b, floatx2 c) {
    floatx2 d;
    asm("v_pk_fma_f32 %0, %1, %2, %3" : "=v"(d) : "v"(a), "v"(b), "v"(c));
    return d;
}

#define K_SIM2M 28.853900817779268f    // 20/ln2 : M = 2^((sim-1)*K_SIM2M)
#define K_M2SIM 0.034657359027997264f  // 0.05*ln2 : sim = 1 + log2(M)*K_M2SIM
#define LDPH 72                        // padded LDS row stride (halves, emd)

// ------ K1: center+normalize over C -> fp16 FRAGMENT order + stats ----------
// 1024 threads: 16 waves. Fragment chunk (kk,t,slot) = channels
// kk*32+(slot>>4)*8..+8 of node t*16+(slot&15), at ((kk*4+t)*64+slot)*8 halves.
// Both global-read passes are float4 (R24).
__global__ void __launch_bounds__(1024, 1)
norm_kernel(const float* __restrict__ support, const float* __restrict__ query,
            _Float16* __restrict__ Vht, _Float16* __restrict__ Uht,
            float* __restrict__ muA, float* __restrict__ nrmA,
            float* __restrict__ Ssc) {
    __shared__ float red1[64][64];    // 16 KB  [group][node]
    __shared__ float red2[64][64];    // 16 KB
    __shared__ float muL[64], invL[64];
    __shared__ float tile[128][65];   // 33.3 KB

    int sid = blockIdx.x;             // 0..287
    const float* src;
    _Float16* dst;
    if (sid < 32) {
        src = support + (size_t)sid * 32768; dst = Vht + (size_t)sid * 32768;
    } else {
        src = query + (size_t)(sid - 32) * 32768; dst = Uht + (size_t)(sid - 32) * 32768;
    }

    // ---- stats pass: float4 over nodes. thread t: group g = (t>>6)*4 +
    // ((t>>4)&3) covers channels g*8..+7; node quad nq = t&15. ----
    {
        int nq = threadIdx.x & 15;
        int g  = ((threadIdx.x >> 6) << 2) | ((threadIdx.x >> 4) & 3);
        float4 s1 = {0.f, 0.f, 0.f, 0.f}, s2 = {0.f, 0.f, 0.f, 0.f};
        const float* base = src + (size_t)g * 8 * 64 + nq * 4;
#pragma unroll
        for (int j = 0; j < 8; ++j) {
            float4 v = *(const float4*)(base + j * 64);
            s1.x += v.x; s1.y += v.y; s1.z += v.z; s1.w += v.w;
            s2.x = fmaf(v.x, v.x, s2.x); s2.y = fmaf(v.y, v.y, s2.y);
            s2.z = fmaf(v.z, v.z, s2.z); s2.w = fmaf(v.w, v.w, s2.w);
        }
        *(float4*)&red1[g][nq * 4] = s1;
        *(float4*)&red2[g][nq * 4] = s2;
    }
    __syncthreads();
    if (threadIdx.x < 64) {
        int node = threadIdx.x;
        float t1 = 0.f, t2 = 0.f;
#pragma unroll
        for (int k = 0; k < 64; ++k) { t1 += red1[k][node]; t2 += red2[k][node]; }
        float mu  = t1 * (1.0f / 512.0f);
        float ss  = t2 - 512.0f * mu * mu;
        float nrm = fmaxf(sqrtf(fmaxf(ss, 0.0f)), 1e-8f);
        muL[node]  = mu;
        invL[node] = 1.0f / nrm;
        muA[sid * 64 + node]  = mu;
        nrmA[sid * 64 + node] = nrm;
        float sS = t1;                 // S = (1/64) sum_{c,m} x
        sS += __shfl_xor(sS, 1);  sS += __shfl_xor(sS, 2);  sS += __shfl_xor(sS, 4);
        sS += __shfl_xor(sS, 8);  sS += __shfl_xor(sS, 16); sS += __shfl_xor(sS, 32);
        if (node == 0) Ssc[sid] = sS * (1.0f / 64.0f);
    }
    __syncthreads();

    // ---- normalize + fragment-order write, slab = 128 channels ----
    for (int ch = 0; ch < 4; ++ch) {
        // float4 load+normalize: thread t: channel c = t>>3, node octet h8 = t&7
        {
            int c  = threadIdx.x >> 3;
            int h8 = threadIdx.x & 7;
            const float* p = src + (size_t)(ch * 128 + c) * 64 + h8 * 8;
            float4 v0 = *(const float4*)p;
            float4 v1 = *(const float4*)(p + 4);
            float4 m0  = *(const float4*)&muL[h8 * 8];
            float4 m1  = *(const float4*)&muL[h8 * 8 + 4];
            float4 i0  = *(const float4*)&invL[h8 * 8];
            float4 i1  = *(const float4*)&invL[h8 * 8 + 4];
            v0.x = (v0.x - m0.x) * i0.x; v0.y = (v0.y - m0.y) * i0.y;
            v0.z = (v0.z - m0.z) * i0.z; v0.w = (v0.w - m0.w) * i0.w;
            v1.x = (v1.x - m1.x) * i1.x; v1.y = (v1.y - m1.y) * i1.y;
            v1.z = (v1.z - m1.z) * i1.z; v1.w = (v1.w - m1.w) * i1.w;
            *(float4*)&tile[c][h8 * 8]     = v0;
            *(float4*)&tile[c][h8 * 8 + 4] = v1;
        }
        __syncthreads();
        // 1024 fragment chunks per slab: exactly one per thread
        {
            int g    = threadIdx.x;    // kkl*256 + t*64 + slot
            int slot = g & 63;
            int t    = (g >> 6) & 3;
            int kkl  = g >> 8;
            int nd   = t * 16 + (slot & 15);
            int c8   = (kkl << 2) | (slot >> 4);
            half8 v;
#pragma unroll
            for (int i = 0; i < 8; ++i) v[i] = (_Float16)tile[c8 * 8 + i][nd];
            *(half8*)(dst + ((size_t)ch * 1024 + g) * 8) = v;
        }
        __syncthreads();
    }
}

// --- K2: FUSED MFMA sim + acc-derived a/b marginals + SOR-Sinkhorn + logits -
// 4 waves/block sharing one w (V loads L1-shared), wave-private LDS, no
// barriers. XCD-resident: blockIdx%8 = XCD owns q in [32x, 32x+32).
__global__ void __launch_bounds__(256, 4)
emd_kernel(const _Float16* __restrict__ Uht, const _Float16* __restrict__ Vht,
           const float* __restrict__ muA, const float* __restrict__ nrmA,
           const float* __restrict__ Ssc, float* __restrict__ out) {
    __shared__ __align__(16) _Float16 T[4][64 * LDPH];   // 36,864 B
    __shared__ float dAB[4][128];                        //  2,048 B

    int x    = blockIdx.x & 7;
    int i    = blockIdx.x >> 3;       // 0..255: (qquad 8) x (w 32)
    int w    = i & 31;
    int wave = threadIdx.x >> 6;      // 0..3
    int lane = threadIdx.x & 63;
    int q    = x * 32 + (i >> 5) * 4 + wave;   // XCD x: q in [32x,32x+32)
    int lo16 = lane & 15;
    int hi4  = lane >> 4;
    int ig   = lane >> 3;
    int jg   = lane & 7;

    // ---- phase 1: sim tile via fp16 MFMA, fragment-order loads ----
    floatx4 acc[4][4];
#pragma unroll
    for (int tm = 0; tm < 4; ++tm)
#pragma unroll
        for (int tn = 0; tn < 4; ++tn)
            acc[tm][tn] = (floatx4){0.f, 0.f, 0.f, 0.f};

    const _Float16* Abase = Uht + (size_t)q * 32768 + lane * 8;
    const _Float16* Bbase = Vht + (size_t)w * 32768 + lane * 8;
#pragma unroll 1
    for (int kk = 0; kk < 16; ++kk) {
        half8 bf[4];
#pragma unroll
        for (int t = 0; t < 4; ++t)
            bf[t] = *(const half8*)(Bbase + (size_t)(kk * 4 + t) * 512);
#pragma unroll
        for (int tm = 0; tm < 4; ++tm) {
            half8 af = *(const half8*)(Abase + (size_t)(kk * 4 + tm) * 512);
#pragma unroll
            for (int tn = 0; tn < 4; ++tn)
                acc[tm][tn] = __builtin_amdgcn_mfma_f32_16x16x32_f16(
                    af, bf[tn], acc[tm][tn], 0, 0, 0);
        }
    }

    // ---- marginal dots from the sim acc (weighted row/col sums) ----
    // dotA[n] = (1/64) sum_m nrm_w[m]*sim[n,m]; dotB[m] = (1/64) sum_n nrm_q[n]*sim[n,m]
    {
        float nw[4];
#pragma unroll
        for (int tn = 0; tn < 4; ++tn)
            nw[tn] = nrmA[w * 64 + tn * 16 + lo16];
        float4 nq[4];
#pragma unroll
        for (int tm = 0; tm < 4; ++tm)
            nq[tm] = *(const float4*)(nrmA + (32 + q) * 64 + tm * 16 + hi4 * 4);

        float pA[4][4];
#pragma unroll
        for (int tm = 0; tm < 4; ++tm)
#pragma unroll
            for (int r = 0; r < 4; ++r) {
                float s = acc[tm][0][r] * nw[0];
                s = fmaf(acc[tm][1][r], nw[1], s);
                s = fmaf(acc[tm][2][r], nw[2], s);
                s = fmaf(acc[tm][3][r], nw[3], s);
                s += __shfl_xor(s, 1); s += __shfl_xor(s, 2);
                s += __shfl_xor(s, 4); s += __shfl_xor(s, 8);
                pA[tm][r] = s;
            }
        float pB[4];
#pragma unroll
        for (int tn = 0; tn < 4; ++tn) {
            float s = acc[0][tn][0] * nq[0].x;
            s = fmaf(acc[0][tn][1], nq[0].y, s);
            s = fmaf(acc[0][tn][2], nq[0].z, s);
            s = fmaf(acc[0][tn][3], nq[0].w, s);
#pragma unroll
            for (int tm = 1; tm < 4; ++tm) {
                s = fmaf(acc[tm][tn][0], nq[tm].x, s);
                s = fmaf(acc[tm][tn][1], nq[tm].y, s);
                s = fmaf(acc[tm][tn][2], nq[tm].z, s);
                s = fmaf(acc[tm][tn][3], nq[tm].w, s);
            }
            s += __shfl_xor(s, 16); s += __shfl_xor(s, 32);
            pB[tn] = s;
        }
        float* dA = dAB[wave];
        float* dB = dAB[wave] + 64;
        if (lo16 == 0) {
#pragma unroll
            for (int tm = 0; tm < 4; ++tm)
#pragma unroll
                for (int r = 0; r < 4; ++r)
                    dA[tm * 16 + hi4 * 4 + r] = pA[tm][r] * 0.015625f;
        }
        if (hi4 == 0) {
#pragma unroll
            for (int tn = 0; tn < 4; ++tn)
                dB[tn * 16 + lo16] = pB[tn] * 0.015625f;
        }
    }

    // ---- wave-uniform tile max for the fp16 rescale ----
    float lmax = -2.0f;
#pragma unroll
    for (int tm = 0; tm < 4; ++tm)
#pragma unroll
        for (int tn = 0; tn < 4; ++tn)
#pragma unroll
            for (int r = 0; r < 4; ++r) lmax = fmaxf(lmax, acc[tm][tn][r]);
    lmax = fmaxf(lmax, __shfl_xor(lmax, 1));
    lmax = fmaxf(lmax, __shfl_xor(lmax, 2));
    lmax = fmaxf(lmax, __shfl_xor(lmax, 4));
    lmax = fmaxf(lmax, __shfl_xor(lmax, 8));
    lmax = fmaxf(lmax, __shfl_xor(lmax, 16));
    lmax = fmaxf(lmax, __shfl_xor(lmax, 32));
    float s0 = lmax;

    // ---- phase 2: exp -> f16 LDS (wave-private, NO barrier) -> packed M ----
    {
        _Float16* buf = T[wave];
#pragma unroll
        for (int tm = 0; tm < 4; ++tm)
#pragma unroll
            for (int tn = 0; tn < 4; ++tn)
#pragma unroll
                for (int r = 0; r < 4; ++r) {
                    int row = tm * 16 + hi4 * 4 + r;
                    int col = tn * 16 + lo16;
                    int sp  = (col & 7) ^ (row >> 3);
                    buf[row * LDPH + (col & ~7) + sp] =
                        (_Float16)fexp2((acc[tm][tn][r] - s0) * K_SIM2M);
                }
    }
    floatx2 Mp[8][4];
    {
        const _Float16* buf = T[wave];
#pragma unroll
        for (int t = 0; t < 8; ++t) {
            half8 h = *(const half8*)(buf + (ig * 8 + (jg ^ t)) * LDPH + jg * 8);
#pragma unroll
            for (int j = 0; j < 4; ++j)
                Mp[t][j] = (floatx2){(float)h[2 * j], (float)h[2 * j + 1]};
        }
    }

    // ---- in-wave a/b marginals ----
    int gp = q * 32 + w;
    float a_own, b_own;
    {
        const float* dA = dAB[wave];
        const float* dB = dAB[wave] + 64;
        float Sw = Ssc[w];
        float Sq = Ssc[32 + q];
        // a: q-node marginal at node = lane
        float muq = muA[(32 + q) * 64 + lane];
        float nrq = nrmA[(32 + q) * 64 + lane];
        float va = fmaxf(fmaf(muq, Sw, nrq * dA[lane]), 0.0f) + 0.001f;
        va += 1e-5f;
        float sa = va;
        sa += __shfl_xor(sa, 1);  sa += __shfl_xor(sa, 2);  sa += __shfl_xor(sa, 4);
        sa += __shfl_xor(sa, 8);  sa += __shfl_xor(sa, 16); sa += __shfl_xor(sa, 32);
        a_own = va * (64.0f / sa);
        // b: w-node marginal at node = jg*8+ig (lane bit-swap)
        int nb = ((lane & 7) << 3) | (lane >> 3);
        float muw = muA[w * 64 + nb];
        float nrw = nrmA[w * 64 + nb];
        float vb = fmaxf(fmaf(muw, Sq, nrw * dB[nb]), 0.0f) + 0.001f;
        vb += 1e-5f;
        float sb = vb;
        sb += __shfl_xor(sb, 1);  sb += __shfl_xor(sb, 2);  sb += __shfl_xor(sb, 4);
        sb += __shfl_xor(sb, 8);  sb += __shfl_xor(sb, 16); sb += __shfl_xor(sb, 32);
        b_own = vb * (64.0f / sb);
    }

    // ---- phase 3: SOR-Sinkhorn on v_pk_fma_f32, tol early exit (1e-5) ----
    floatx2 wv2[4];
#pragma unroll
    for (int j = 0; j < 4; ++j) wv2[j] = (floatx2){1.f, 1.f};
    float q8[8];
    float w_prev = -1.f;

#pragma unroll 1
    for (int it = 0; it < 100; ++it) {
        float p[8];
#pragma unroll
        for (int t = 0; t < 8; ++t) {
            floatx2 s2 = pk_mul(Mp[t][0], wv2[0]);
            s2 = pk_fma(Mp[t][1], wv2[1], s2);
            s2 = pk_fma(Mp[t][2], wv2[2], s2);
            s2 = pk_fma(Mp[t][3], wv2[3], s2);
            p[t] = s2[0] + s2[1];
        }
        p[0] += __shfl_xor(p[4], 4); p[1] += __shfl_xor(p[5], 4);
        p[2] += __shfl_xor(p[6], 4); p[3] += __shfl_xor(p[7], 4);
        p[0] += __shfl_xor(p[2], 2); p[1] += __shfl_xor(p[3], 2);
        p[0] += __shfl_xor(p[1], 1);
        float z_own = a_own * fast_rcp(p[0]);
        q8[0] = z_own;
        q8[1] = __shfl_xor(q8[0], 1);
        q8[2] = __shfl_xor(q8[0], 2); q8[3] = __shfl_xor(q8[1], 2);
        q8[4] = __shfl_xor(q8[0], 4); q8[5] = __shfl_xor(q8[1], 4);
        q8[6] = __shfl_xor(q8[2], 4); q8[7] = __shfl_xor(q8[3], 4);
        floatx2 c2[4];
#pragma unroll
        for (int j = 0; j < 4; ++j) {
            floatx2 qb0 = (floatx2){q8[0], q8[0]};
            c2[j] = pk_mul(Mp[0][j], qb0);
        }
#pragma unroll
        for (int t = 1; t < 8; ++t) {
            floatx2 qb = (floatx2){q8[t], q8[t]};
#pragma unroll
            for (int j = 0; j < 4; ++j)
                c2[j] = pk_fma(Mp[t][j], qb, c2[j]);
        }
        float cp[8];
#pragma unroll
        for (int j = 0; j < 4; ++j) { cp[2 * j] = c2[j][0]; cp[2 * j + 1] = c2[j][1]; }
        cp[0] += __shfl_xor(cp[4], 32); cp[1] += __shfl_xor(cp[5], 32);
        cp[2] += __shfl_xor(cp[6], 32); cp[3] += __shfl_xor(cp[7], 32);
        cp[0] += __shfl_xor(cp[2], 16); cp[1] += __shfl_xor(cp[3], 16);
        cp[0] += __shfl_xor(cp[1], 8);
        float w_own = b_own * fast_rcp(cp[0]);   // = F(w_carried)
        // SOR extrapolation on the carried variable (fixed point unchanged):
        // it=0 seeds plain; guard keeps positivity under overshoot.
        float w_car = (it == 0)
            ? w_own
            : fmaxf(fmaf(1.4f, w_own - w_prev, w_prev), 0.1f * w_own);
        float w8_0 = w_car;
        float w8_1 = __shfl_xor(w8_0, 8);
        float w8_2 = __shfl_xor(w8_0, 16), w8_3 = __shfl_xor(w8_1, 16);
        float w8_4 = __shfl_xor(w8_0, 32), w8_5 = __shfl_xor(w8_1, 32);
        float w8_6 = __shfl_xor(w8_2, 32), w8_7 = __shfl_xor(w8_3, 32);
        wv2[0] = (floatx2){w8_0, w8_1};
        wv2[1] = (floatx2){w8_2, w8_3};
        wv2[2] = (floatx2){w8_4, w8_5};
        wv2[3] = (floatx2){w8_6, w8_7};
        // converged when F(w_carried) ~= w_carried (all 64 cols stable)
        bool same = fabsf(w_own - w_prev) <= 1e-5f * w_own;
        w_prev = w_car;
        if (__all(same)) break;
    }

    // ---- phase 4: logits; sim = s0 + log2(M')*eps*ln2 ----
    float s = 0.f;
#pragma unroll
    for (int t = 0; t < 8; ++t)
#pragma unroll
        for (int c = 0; c < 8; ++c) {
            float m    = fmaxf(Mp[t][c >> 1][c & 1], 1e-30f);
            float sim  = fmaf(flog2(m), K_M2SIM, s0);
            float flow = q8[t] * m * wv2[c >> 1][c & 1];
            s = fmaf(sim, flow, s);
        }
    s += __shfl_xor(s, 1);  s += __shfl_xor(s, 2);  s += __shfl_xor(s, 4);
    s += __shfl_xor(s, 8);  s += __shfl_xor(s, 16); s += __shfl_xor(s, 32);
    if (lane == 0) out[gp] = s * 0.1953125f;   // 12.5/64
}

// ---------------------------------------------------------------------------
extern "C" void kernel_launch(void* const* d_in, const int* in_sizes, int n_in,
                              void* d_out, int out_size, void* d_ws, size_t ws_size,
                              hipStream_t stream) {
    (void)in_sizes; (void)n_in; (void)out_size; (void)ws_size;
    const float* support = (const float*)d_in[0];   // 32*512*64
    const float* query   = (const float*)d_in[1];   // 256*512*64

    char* ws = (char*)d_ws;
    _Float16* Uht  = (_Float16*)ws;                 // 16 MB (fragment order)
    _Float16* Vht  = Uht + 8388608;                 //  2 MB (fragment order)
    float* muA  = (float*)(Vht + 1048576);          // 72 KB [288][64]
    float* nrmA = muA + 18432;                      // 72 KB
    float* Ssc  = nrmA + 18432;                     // ~1 KB [288]  (~18.1 MB total)

    norm_kernel<<<288, 1024, 0, stream>>>(support, query, Vht, Uht,
                                          muA, nrmA, Ssc);
    emd_kernel<<<2048, 256, 0, stream>>>(Uht, Vht, muA, nrmA, Ssc,
                                         (float*)d_out);
}

// Round 15
// 147.512 us; speedup vs baseline: 1.1000x; 1.1000x over previous
//
#include <hip/hip_runtime.h>
#include <math.h>

// ---------------------------------------------------------------------------
// EMD layer (Sinkhorn-OT logits) for MI355X.
// support: [32,512,8,8] f32, query: [256,512,8,8] f32 -> logits [256,32] f32.
//
// R26 == R24 (best verified: 147.7us; session start 183.7us).
//   R25's SOR (omega=1.4) REJECTED: emd 71.5->86.5us. Sinkhorn's alternating
//   row/col scaling has oscillatory error modes (complex/negative spectrum);
//   omega>1 amplifies them -> MORE iterations. Algorithmic-acceleration
//   avenue closed alongside: VALU thinning (R19 null), hop reduction (R21
//   regression), tol loosening (R22 post-timing reject).
//   Final config:
//   - norm: monolithic, float4 both global passes, fragment-order f16 out.
//   - emd: fused MFMA sim + acc-derived marginals (weighted row/col sums of
//     the sim accumulator; zero extra MFMA) + pk-fma Sinkhorn with
//     reduce-scatter+gather shuffles, 4-wave blocks sharing w, wave-private
//     LDS (no barriers), XCD-resident q-groups, tol 1e-5.
// ---------------------------------------------------------------------------

#define DEV static __device__ __forceinline__

typedef _Float16 half8 __attribute__((ext_vector_type(8)));
typedef float floatx4 __attribute__((ext_vector_type(4)));
typedef float floatx2 __attribute__((ext_vector_type(2)));

DEV float fast_rcp(float x) {
#if __has_builtin(__builtin_amdgcn_rcpf)
    return __builtin_amdgcn_rcpf(x);
#else
    return 1.0f / x;
#endif
}
DEV float fexp2(float x) {
#if __has_builtin(__builtin_amdgcn_exp2f)
    return __builtin_amdgcn_exp2f(x);
#else
    return exp2f(x);
#endif
}
DEV float flog2(float x) {
#if __has_builtin(__builtin_amdgcn_logf)
    return __builtin_amdgcn_logf(x);
#else
    return log2f(x);
#endif
}
DEV floatx2 pk_mul(floatx2 a, floatx2 b) {
    floatx2 d;
    asm("v_pk_mul_f32 %0, %1, %2" : "=v"(d) : "v"(a), "v"(b));
    return d;
}
DEV floatx2 pk_fma(floatx2 a, floatx2 b, floatx2 c) {
    floatx2 d;
    asm("v_pk_fma_f32 %0, %1, %2, %3" : "=v"(d) : "v"(a), "v"(b), "v"(c));
    return d;
}

#define K_SIM2M 28.853900817779268f    // 20/ln2 : M = 2^((sim-1)*K_SIM2M)
#define K_M2SIM 0.034657359027997264f  // 0.05*ln2 : sim = 1 + log2(M)*K_M2SIM
#define LDPH 72                        // padded LDS row stride (halves, emd)

// ------ K1: center+normalize over C -> fp16 FRAGMENT order + stats ----------
// 1024 threads: 16 waves. Fragment chunk (kk,t,slot) = channels
// kk*32+(slot>>4)*8..+8 of node t*16+(slot&15), at ((kk*4+t)*64+slot)*8 halves.
// Both global-read passes are float4.
__global__ void __launch_bounds__(1024, 1)
norm_kernel(const float* __restrict__ support, const float* __restrict__ query,
            _Float16* __restrict__ Vht, _Float16* __restrict__ Uht,
            float* __restrict__ muA, float* __restrict__ nrmA,
            float* __restrict__ Ssc) {
    __shared__ float red1[64][64];    // 16 KB  [group][node]
    __shared__ float red2[64][64];    // 16 KB
    __shared__ float muL[64], invL[64];
    __shared__ float tile[128][65];   // 33.3 KB

    int sid = blockIdx.x;             // 0..287
    const float* src;
    _Float16* dst;
    if (sid < 32) {
        src = support + (size_t)sid * 32768; dst = Vht + (size_t)sid * 32768;
    } else {
        src = query + (size_t)(sid - 32) * 32768; dst = Uht + (size_t)(sid - 32) * 32768;
    }

    // ---- stats pass: float4 over nodes. thread t: group g = (t>>6)*4 +
    // ((t>>4)&3) covers channels g*8..+7; node quad nq = t&15. ----
    {
        int nq = threadIdx.x & 15;
        int g  = ((threadIdx.x >> 6) << 2) | ((threadIdx.x >> 4) & 3);
        float4 s1 = {0.f, 0.f, 0.f, 0.f}, s2 = {0.f, 0.f, 0.f, 0.f};
        const float* base = src + (size_t)g * 8 * 64 + nq * 4;
#pragma unroll
        for (int j = 0; j < 8; ++j) {
            float4 v = *(const float4*)(base + j * 64);
            s1.x += v.x; s1.y += v.y; s1.z += v.z; s1.w += v.w;
            s2.x = fmaf(v.x, v.x, s2.x); s2.y = fmaf(v.y, v.y, s2.y);
            s2.z = fmaf(v.z, v.z, s2.z); s2.w = fmaf(v.w, v.w, s2.w);
        }
        *(float4*)&red1[g][nq * 4] = s1;
        *(float4*)&red2[g][nq * 4] = s2;
    }
    __syncthreads();
    if (threadIdx.x < 64) {
        int node = threadIdx.x;
        float t1 = 0.f, t2 = 0.f;
#pragma unroll
        for (int k = 0; k < 64; ++k) { t1 += red1[k][node]; t2 += red2[k][node]; }
        float mu  = t1 * (1.0f / 512.0f);
        float ss  = t2 - 512.0f * mu * mu;
        float nrm = fmaxf(sqrtf(fmaxf(ss, 0.0f)), 1e-8f);
        muL[node]  = mu;
        invL[node] = 1.0f / nrm;
        muA[sid * 64 + node]  = mu;
        nrmA[sid * 64 + node] = nrm;
        float sS = t1;                 // S = (1/64) sum_{c,m} x
        sS += __shfl_xor(sS, 1);  sS += __shfl_xor(sS, 2);  sS += __shfl_xor(sS, 4);
        sS += __shfl_xor(sS, 8);  sS += __shfl_xor(sS, 16); sS += __shfl_xor(sS, 32);
        if (node == 0) Ssc[sid] = sS * (1.0f / 64.0f);
    }
    __syncthreads();

    // ---- normalize + fragment-order write, slab = 128 channels ----
    for (int ch = 0; ch < 4; ++ch) {
        // float4 load+normalize: thread t: channel c = t>>3, node octet h8 = t&7
        {
            int c  = threadIdx.x >> 3;
            int h8 = threadIdx.x & 7;
            const float* p = src + (size_t)(ch * 128 + c) * 64 + h8 * 8;
            float4 v0 = *(const float4*)p;
            float4 v1 = *(const float4*)(p + 4);
            float4 m0  = *(const float4*)&muL[h8 * 8];
            float4 m1  = *(const float4*)&muL[h8 * 8 + 4];
            float4 i0  = *(const float4*)&invL[h8 * 8];
            float4 i1  = *(const float4*)&invL[h8 * 8 + 4];
            v0.x = (v0.x - m0.x) * i0.x; v0.y = (v0.y - m0.y) * i0.y;
            v0.z = (v0.z - m0.z) * i0.z; v0.w = (v0.w - m0.w) * i0.w;
            v1.x = (v1.x - m1.x) * i1.x; v1.y = (v1.y - m1.y) * i1.y;
            v1.z = (v1.z - m1.z) * i1.z; v1.w = (v1.w - m1.w) * i1.w;
            *(float4*)&tile[c][h8 * 8]     = v0;
            *(float4*)&tile[c][h8 * 8 + 4] = v1;
        }
        __syncthreads();
        // 1024 fragment chunks per slab: exactly one per thread
        {
            int g    = threadIdx.x;    // kkl*256 + t*64 + slot
            int slot = g & 63;
            int t    = (g >> 6) & 3;
            int kkl  = g >> 8;
            int nd   = t * 16 + (slot & 15);
            int c8   = (kkl << 2) | (slot >> 4);
            half8 v;
#pragma unroll
            for (int i = 0; i < 8; ++i) v[i] = (_Float16)tile[c8 * 8 + i][nd];
            *(half8*)(dst + ((size_t)ch * 1024 + g) * 8) = v;
        }
        __syncthreads();
    }
}

// --- K2: FUSED MFMA sim + acc-derived a/b marginals + pk-Sinkhorn + logits --
// 4 waves/block sharing one w (V loads L1-shared), wave-private LDS, no
// barriers. XCD-resident: blockIdx%8 = XCD owns q in [32x, 32x+32).
__global__ void __launch_bounds__(256, 4)
emd_kernel(const _Float16* __restrict__ Uht, const _Float16* __restrict__ Vht,
           const float* __restrict__ muA, const float* __restrict__ nrmA,
           const float* __restrict__ Ssc, float* __restrict__ out) {
    __shared__ __align__(16) _Float16 T[4][64 * LDPH];   // 36,864 B
    __shared__ float dAB[4][128];                        //  2,048 B

    int x    = blockIdx.x & 7;
    int i    = blockIdx.x >> 3;       // 0..255: (qquad 8) x (w 32)
    int w    = i & 31;
    int wave = threadIdx.x >> 6;      // 0..3
    int lane = threadIdx.x & 63;
    int q    = x * 32 + (i >> 5) * 4 + wave;   // XCD x: q in [32x,32x+32)
    int lo16 = lane & 15;
    int hi4  = lane >> 4;
    int ig   = lane >> 3;
    int jg   = lane & 7;

    // ---- phase 1: sim tile via fp16 MFMA, fragment-order loads ----
    floatx4 acc[4][4];
#pragma unroll
    for (int tm = 0; tm < 4; ++tm)
#pragma unroll
        for (int tn = 0; tn < 4; ++tn)
            acc[tm][tn] = (floatx4){0.f, 0.f, 0.f, 0.f};

    const _Float16* Abase = Uht + (size_t)q * 32768 + lane * 8;
    const _Float16* Bbase = Vht + (size_t)w * 32768 + lane * 8;
#pragma unroll 1
    for (int kk = 0; kk < 16; ++kk) {
        half8 bf[4];
#pragma unroll
        for (int t = 0; t < 4; ++t)
            bf[t] = *(const half8*)(Bbase + (size_t)(kk * 4 + t) * 512);
#pragma unroll
        for (int tm = 0; tm < 4; ++tm) {
            half8 af = *(const half8*)(Abase + (size_t)(kk * 4 + tm) * 512);
#pragma unroll
            for (int tn = 0; tn < 4; ++tn)
                acc[tm][tn] = __builtin_amdgcn_mfma_f32_16x16x32_f16(
                    af, bf[tn], acc[tm][tn], 0, 0, 0);
        }
    }

    // ---- marginal dots from the sim acc (weighted row/col sums) ----
    // dotA[n] = (1/64) sum_m nrm_w[m]*sim[n,m]; dotB[m] = (1/64) sum_n nrm_q[n]*sim[n,m]
    {
        float nw[4];
#pragma unroll
        for (int tn = 0; tn < 4; ++tn)
            nw[tn] = nrmA[w * 64 + tn * 16 + lo16];
        float4 nq[4];
#pragma unroll
        for (int tm = 0; tm < 4; ++tm)
            nq[tm] = *(const float4*)(nrmA + (32 + q) * 64 + tm * 16 + hi4 * 4);

        float pA[4][4];
#pragma unroll
        for (int tm = 0; tm < 4; ++tm)
#pragma unroll
            for (int r = 0; r < 4; ++r) {
                float s = acc[tm][0][r] * nw[0];
                s = fmaf(acc[tm][1][r], nw[1], s);
                s = fmaf(acc[tm][2][r], nw[2], s);
                s = fmaf(acc[tm][3][r], nw[3], s);
                s += __shfl_xor(s, 1); s += __shfl_xor(s, 2);
                s += __shfl_xor(s, 4); s += __shfl_xor(s, 8);
                pA[tm][r] = s;
            }
        float pB[4];
#pragma unroll
        for (int tn = 0; tn < 4; ++tn) {
            float s = acc[0][tn][0] * nq[0].x;
            s = fmaf(acc[0][tn][1], nq[0].y, s);
            s = fmaf(acc[0][tn][2], nq[0].z, s);
            s = fmaf(acc[0][tn][3], nq[0].w, s);
#pragma unroll
            for (int tm = 1; tm < 4; ++tm) {
                s = fmaf(acc[tm][tn][0], nq[tm].x, s);
                s = fmaf(acc[tm][tn][1], nq[tm].y, s);
                s = fmaf(acc[tm][tn][2], nq[tm].z, s);
                s = fmaf(acc[tm][tn][3], nq[tm].w, s);
            }
            s += __shfl_xor(s, 16); s += __shfl_xor(s, 32);
            pB[tn] = s;
        }
        float* dA = dAB[wave];
        float* dB = dAB[wave] + 64;
        if (lo16 == 0) {
#pragma unroll
            for (int tm = 0; tm < 4; ++tm)
#pragma unroll
                for (int r = 0; r < 4; ++r)
                    dA[tm * 16 + hi4 * 4 + r] = pA[tm][r] * 0.015625f;
        }
        if (hi4 == 0) {
#pragma unroll
            for (int tn = 0; tn < 4; ++tn)
                dB[tn * 16 + lo16] = pB[tn] * 0.015625f;
        }
    }

    // ---- wave-uniform tile max for the fp16 rescale ----
    float lmax = -2.0f;
#pragma unroll
    for (int tm = 0; tm < 4; ++tm)
#pragma unroll
        for (int tn = 0; tn < 4; ++tn)
#pragma unroll
            for (int r = 0; r < 4; ++r) lmax = fmaxf(lmax, acc[tm][tn][r]);
    lmax = fmaxf(lmax, __shfl_xor(lmax, 1));
    lmax = fmaxf(lmax, __shfl_xor(lmax, 2));
    lmax = fmaxf(lmax, __shfl_xor(lmax, 4));
    lmax = fmaxf(lmax, __shfl_xor(lmax, 8));
    lmax = fmaxf(lmax, __shfl_xor(lmax, 16));
    lmax = fmaxf(lmax, __shfl_xor(lmax, 32));
    float s0 = lmax;

    // ---- phase 2: exp -> f16 LDS (wave-private, NO barrier) -> packed M ----
    {
        _Float16* buf = T[wave];
#pragma unroll
        for (int tm = 0; tm < 4; ++tm)
#pragma unroll
            for (int tn = 0; tn < 4; ++tn)
#pragma unroll
                for (int r = 0; r < 4; ++r) {
                    int row = tm * 16 + hi4 * 4 + r;
                    int col = tn * 16 + lo16;
                    int sp  = (col & 7) ^ (row >> 3);
                    buf[row * LDPH + (col & ~7) + sp] =
                        (_Float16)fexp2((acc[tm][tn][r] - s0) * K_SIM2M);
                }
    }
    floatx2 Mp[8][4];
    {
        const _Float16* buf = T[wave];
#pragma unroll
        for (int t = 0; t < 8; ++t) {
            half8 h = *(const half8*)(buf + (ig * 8 + (jg ^ t)) * LDPH + jg * 8);
#pragma unroll
            for (int j = 0; j < 4; ++j)
                Mp[t][j] = (floatx2){(float)h[2 * j], (float)h[2 * j + 1]};
        }
    }

    // ---- in-wave a/b marginals ----
    int gp = q * 32 + w;
    float a_own, b_own;
    {
        const float* dA = dAB[wave];
        const float* dB = dAB[wave] + 64;
        float Sw = Ssc[w];
        float Sq = Ssc[32 + q];
        // a: q-node marginal at node = lane
        float muq = muA[(32 + q) * 64 + lane];
        float nrq = nrmA[(32 + q) * 64 + lane];
        float va = fmaxf(fmaf(muq, Sw, nrq * dA[lane]), 0.0f) + 0.001f;
        va += 1e-5f;
        float sa = va;
        sa += __shfl_xor(sa, 1);  sa += __shfl_xor(sa, 2);  sa += __shfl_xor(sa, 4);
        sa += __shfl_xor(sa, 8);  sa += __shfl_xor(sa, 16); sa += __shfl_xor(sa, 32);
        a_own = va * (64.0f / sa);
        // b: w-node marginal at node = jg*8+ig (lane bit-swap)
        int nb = ((lane & 7) << 3) | (lane >> 3);
        float muw = muA[w * 64 + nb];
        float nrw = nrmA[w * 64 + nb];
        float vb = fmaxf(fmaf(muw, Sq, nrw * dB[nb]), 0.0f) + 0.001f;
        vb += 1e-5f;
        float sb = vb;
        sb += __shfl_xor(sb, 1);  sb += __shfl_xor(sb, 2);  sb += __shfl_xor(sb, 4);
        sb += __shfl_xor(sb, 8);  sb += __shfl_xor(sb, 16); sb += __shfl_xor(sb, 32);
        b_own = vb * (64.0f / sb);
    }

    // ---- phase 3: Sinkhorn on v_pk_fma_f32, tol early exit (1e-5) ----
    floatx2 wv2[4];
#pragma unroll
    for (int j = 0; j < 4; ++j) wv2[j] = (floatx2){1.f, 1.f};
    float q8[8];
    float w_prev = -1.f;

#pragma unroll 1
    for (int it = 0; it < 100; ++it) {
        float p[8];
#pragma unroll
        for (int t = 0; t < 8; ++t) {
            floatx2 s2 = pk_mul(Mp[t][0], wv2[0]);
            s2 = pk_fma(Mp[t][1], wv2[1], s2);
            s2 = pk_fma(Mp[t][2], wv2[2], s2);
            s2 = pk_fma(Mp[t][3], wv2[3], s2);
            p[t] = s2[0] + s2[1];
        }
        p[0] += __shfl_xor(p[4], 4); p[1] += __shfl_xor(p[5], 4);
        p[2] += __shfl_xor(p[6], 4); p[3] += __shfl_xor(p[7], 4);
        p[0] += __shfl_xor(p[2], 2); p[1] += __shfl_xor(p[3], 2);
        p[0] += __shfl_xor(p[1], 1);
        float z_own = a_own * fast_rcp(p[0]);
        q8[0] = z_own;
        q8[1] = __shfl_xor(q8[0], 1);
        q8[2] = __shfl_xor(q8[0], 2); q8[3] = __shfl_xor(q8[1], 2);
        q8[4] = __shfl_xor(q8[0], 4); q8[5] = __shfl_xor(q8[1], 4);
        q8[6] = __shfl_xor(q8[2], 4); q8[7] = __shfl_xor(q8[3], 4);
        floatx2 c2[4];
#pragma unroll
        for (int j = 0; j < 4; ++j) {
            floatx2 qb0 = (floatx2){q8[0], q8[0]};
            c2[j] = pk_mul(Mp[0][j], qb0);
        }
#pragma unroll
        for (int t = 1; t < 8; ++t) {
            floatx2 qb = (floatx2){q8[t], q8[t]};
#pragma unroll
            for (int j = 0; j < 4; ++j)
                c2[j] = pk_fma(Mp[t][j], qb, c2[j]);
        }
        float cp[8];
#pragma unroll
        for (int j = 0; j < 4; ++j) { cp[2 * j] = c2[j][0]; cp[2 * j + 1] = c2[j][1]; }
        cp[0] += __shfl_xor(cp[4], 32); cp[1] += __shfl_xor(cp[5], 32);
        cp[2] += __shfl_xor(cp[6], 32); cp[3] += __shfl_xor(cp[7], 32);
        cp[0] += __shfl_xor(cp[2], 16); cp[1] += __shfl_xor(cp[3], 16);
        cp[0] += __shfl_xor(cp[1], 8);
        float w_own = b_own * fast_rcp(cp[0]);
        float w8_0 = w_own;
        float w8_1 = __shfl_xor(w8_0, 8);
        float w8_2 = __shfl_xor(w8_0, 16), w8_3 = __shfl_xor(w8_1, 16);
        float w8_4 = __shfl_xor(w8_0, 32), w8_5 = __shfl_xor(w8_1, 32);
        float w8_6 = __shfl_xor(w8_2, 32), w8_7 = __shfl_xor(w8_3, 32);
        wv2[0] = (floatx2){w8_0, w8_1};
        wv2[1] = (floatx2){w8_2, w8_3};
        wv2[2] = (floatx2){w8_4, w8_5};
        wv2[3] = (floatx2){w8_6, w8_7};
        // w stable across all 64 cols -> next z,w identical -> fixed point
        bool same = fabsf(w_own - w_prev) <= 1e-5f * w_own;
        w_prev = w_own;
        if (__all(same)) break;
    }

    // ---- phase 4: logits; sim = s0 + log2(M')*eps*ln2 ----
    float s = 0.f;
#pragma unroll
    for (int t = 0; t < 8; ++t)
#pragma unroll
        for (int c = 0; c < 8; ++c) {
            float m    = fmaxf(Mp[t][c >> 1][c & 1], 1e-30f);
            float sim  = fmaf(flog2(m), K_M2SIM, s0);
            float flow = q8[t] * m * wv2[c >> 1][c & 1];
            s = fmaf(sim, flow, s);
        }
    s += __shfl_xor(s, 1);  s += __shfl_xor(s, 2);  s += __shfl_xor(s, 4);
    s += __shfl_xor(s, 8);  s += __shfl_xor(s, 16); s += __shfl_xor(s, 32);
    if (lane == 0) out[gp] = s * 0.1953125f;   // 12.5/64
}

// ---------------------------------------------------------------------------
extern "C" void kernel_launch(void* const* d_in, const int* in_sizes, int n_in,
                              void* d_out, int out_size, void* d_ws, size_t ws_size,
                              hipStream_t stream) {
    (void)in_sizes; (void)n_in; (void)out_size; (void)ws_size;
    const float* support = (const float*)d_in[0];   // 32*512*64
    const float* query   = (const float*)d_in[1];   // 256*512*64

    char* ws = (char*)d_ws;
    _Float16* Uht  = (_Float16*)ws;                 // 16 MB (fragment order)
    _Float16* Vht  = Uht + 8388608;                 //  2 MB (fragment order)
    float* muA  = (float*)(Vht + 1048576);          // 72 KB [288][64]
    float* nrmA = muA + 18432;                      // 72 KB
    float* Ssc  = nrmA + 18432;                     // ~1 KB [288]  (~18.1 MB total)

    norm_kernel<<<288, 1024, 0, stream>>>(support, query, Vht, Uht,
                                          muA, nrmA, Ssc);
    emd_kernel<<<2048, 256, 0, stream>>>(Uht, Vht, muA, nrmA, Ssc,
                                         (float*)d_out);
}